// Round 1
// baseline (357.164 us; speedup 1.0000x reference)
//
#include <hip/hip_runtime.h>

// HashRouter: h = x @ W^T + b  (T x 64), bits = h>0, cand = popcount per 32-bit
// group (<=32, so %64 is identity), linear probe with NUM_SELECTED=2:
//   i0 = c0 ; i1 = c1 + (c1 == c0)   (c1+1 <= 33 < 64, never wraps)
// Outputs (float32, concat): weights[T][2]=0.5, indices[T][2], logits[T][64]=0.

constexpr int H_DIM   = 2048;
constexpr int NJ      = 64;   // hash outputs per token
constexpr int TOK     = 64;   // tokens per block
constexpr int KC      = 64;   // k-chunk staged in LDS
constexpr int LSTRIDE = 68;   // KC + 4 pad (keeps 16B alignment, breaks pow2 stride)

__global__ __launch_bounds__(256) void hash_router_kernel(
    const float* __restrict__ x,   // [T, H]
    const float* __restrict__ w,   // [64, H]
    const float* __restrict__ b,   // [64]
    float* __restrict__ out,       // [2T | 2T | 64T]
    int T)
{
    __shared__ float xs[TOK][LSTRIDE];
    __shared__ float ws[NJ][LSTRIDE];
    __shared__ unsigned int bitw[TOK][2];

    const int tid  = threadIdx.x;
    const int jj   = tid & 15;   // output group: handles outputs jj*4 .. jj*4+3
    const int tt   = tid >> 4;   // token group:  handles tokens  tt*4 .. tt*4+3
    const int tok0 = blockIdx.x * TOK;

    if (tid < TOK * 2) ((unsigned int*)bitw)[tid] = 0u;

    float bias[4];
#pragma unroll
    for (int c = 0; c < 4; ++c) bias[c] = b[jj * 4 + c];

    float acc[4][4];
#pragma unroll
    for (int t = 0; t < 4; ++t)
#pragma unroll
        for (int c = 0; c < 4; ++c) acc[t][c] = bias[c];

    const int lrow = tid >> 4;   // loader: 16 rows/pass, 4 passes
    const int lcol = tid & 15;   // loader: float4 column

    for (int k0 = 0; k0 < H_DIM; k0 += KC) {
        __syncthreads();   // previous chunk's readers done before overwrite
#pragma unroll
        for (int p = 0; p < 4; ++p) {
            const int row = lrow + p * 16;
            const float4 xv = *(const float4*)(x + (size_t)(tok0 + row) * H_DIM + k0 + lcol * 4);
            *(float4*)(&xs[row][lcol * 4]) = xv;
            const float4 wv = *(const float4*)(w + (size_t)row * H_DIM + k0 + lcol * 4);
            *(float4*)(&ws[row][lcol * 4]) = wv;
        }
        __syncthreads();

#pragma unroll 4
        for (int k4 = 0; k4 < KC / 4; ++k4) {
            float4 xv[4], wv[4];
#pragma unroll
            for (int i = 0; i < 4; ++i) xv[i] = *(const float4*)(&xs[tt * 4 + i][k4 * 4]);
#pragma unroll
            for (int i = 0; i < 4; ++i) wv[i] = *(const float4*)(&ws[jj * 4 + i][k4 * 4]);
#pragma unroll
            for (int t = 0; t < 4; ++t)
#pragma unroll
                for (int c = 0; c < 4; ++c) {
                    acc[t][c] += xv[t].x * wv[c].x;
                    acc[t][c] += xv[t].y * wv[c].y;
                    acc[t][c] += xv[t].z * wv[c].z;
                    acc[t][c] += xv[t].w * wv[c].w;
                }
        }
    }

    // Sign extraction. For |h| within fp32-accumulation noise of 0, recompute
    // that single dot product in fp64 so our sign is mathematically exact
    // (reference threshold requires exact index match). Expected ~100 such
    // dots across the whole GPU -> negligible cost.
    const float TH = 5e-5f;
#pragma unroll
    for (int t = 0; t < 4; ++t) {
        unsigned int nib = 0u;
#pragma unroll
        for (int c = 0; c < 4; ++c) {
            const float v = acc[t][c];
            bool pos;
            if (__builtin_expect(fabsf(v) < TH, 0)) {
                const float* xr = x + (size_t)(tok0 + tt * 4 + t) * H_DIM;
                const float* wr = w + (size_t)(jj * 4 + c) * H_DIM;
                double s = (double)bias[c];
                for (int k = 0; k < H_DIM; ++k)
                    s += (double)xr[k] * (double)wr[k];
                pos = (s > 0.0);
            } else {
                pos = (v > 0.0f);
            }
            nib |= (pos ? 1u : 0u) << c;
        }
        // outputs jj*4..jj*4+3 all lie in 32-bit group (jj>>3); bit position
        // within the group is irrelevant (only popcount matters)
        if (nib) atomicOr(&bitw[tt * 4 + t][jj >> 3], nib << ((jj & 7) * 4));
    }
    __syncthreads();

    if (tid < TOK) {
        const int t  = tok0 + tid;
        const int c0 = __popc(bitw[tid][0]);
        const int c1 = __popc(bitw[tid][1]);
        const int i0 = c0;
        const int i1 = c1 + ((c1 == c0) ? 1 : 0);
        float2 wq; wq.x = 0.5f; wq.y = 0.5f;
        *(float2*)(out + 2 * (size_t)t) = wq;
        float2 iq; iq.x = (float)i0; iq.y = (float)i1;
        *(float2*)(out + 2 * (size_t)T + 2 * (size_t)t) = iq;
    }

    // router_logits = 0 (d_out is poisoned 0xAA before every timed launch)
    float4 z; z.x = 0.f; z.y = 0.f; z.z = 0.f; z.w = 0.f;
    float* lbase = out + 4 * (size_t)T + (size_t)tok0 * NJ;
    for (int i = tid; i < TOK * NJ / 4; i += 256)
        *(float4*)(lbase + i * 4) = z;
}

extern "C" void kernel_launch(void* const* d_in, const int* in_sizes, int n_in,
                              void* d_out, int out_size, void* d_ws, size_t ws_size,
                              hipStream_t stream) {
    const float* x = (const float*)d_in[0];
    const float* w = (const float*)d_in[1];
    const float* b = (const float*)d_in[2];
    float* out = (float*)d_out;
    const int T = in_sizes[0] / H_DIM;      // 16384
    const int grid = T / TOK;               // 256
    hash_router_kernel<<<dim3(grid), dim3(256), 0, stream>>>(x, w, b, out, T);
}